// Round 6
// baseline (148.223 us; speedup 1.0000x reference)
//
#include <hip/hip_runtime.h>
#include <hip/hip_cooperative_groups.h>
#include <math.h>

namespace cg = cooperative_groups;
typedef unsigned long long u64;

#define B 512
#define M 4096
#define T 48
#define MCHUNK 8
#define NCH (M / MCHUNK)   // 512 chunks; grid = 512 blocks

// ws layout (bytes):
//   [0, 2 MiB)            pvalT[ch][b]: packed (float_bits(dist)<<32 | m), u64
//   [2 MiB, 2 MiB+192KiB) tgtP[q][b]: float4 (t=2q,2q+1), q<24

__global__ __launch_bounds__(256, 2) void k_fused(const float* __restrict__ preds,
                                                  const float* __restrict__ target,
                                                  const float* __restrict__ memory,
                                                  float* __restrict__ out,
                                                  u64* __restrict__ pvalT,
                                                  float4* __restrict__ tgtP) {
    cg::grid_group grid = cg::this_grid();
    const int tid = threadIdx.x;
    const int bid = blockIdx.x;

    __shared__ float4 smem[MCHUNK * (T / 2)];     // 192 float4 = 3 KB
    __shared__ u64    smu[256];                   // 2 KB
    __shared__ float  red[256];                   // 1 KB

    // ---------------- Phase 0: pack target (B,T,2) -> tgtP[q][b] ----------------
    {
        int i = bid * 256 + tid;                  // 48 blocks' worth of work
        if (i < B * (T / 2)) {
            int b = i / (T / 2), q = i - b * (T / 2);
            float4 v = *(const float4*)(target + (size_t)b * (T * 2) + 4 * q);
            tgtP[q * B + b] = v;
        }
        if (i == 0) out[0] = 0.0f;
    }
    grid.sync();

    // ---------------- Phase 1: distances (block = m-chunk, thread = 2 b's) ------
    {
        const int ch = bid;
        const int m0 = ch * MCHUNK;
        if (tid < MCHUNK * (T / 2))
            smem[tid] = ((const float4*)(memory + (size_t)m0 * (T * 2)))[tid];
        __syncthreads();

        float acc0[MCHUNK], acc1[MCHUNK];
#pragma unroll
        for (int i = 0; i < MCHUNK; ++i) { acc0[i] = 0.f; acc1[i] = 0.f; }

#pragma unroll 4
        for (int q = 0; q < T / 2; ++q) {
            float4 g0 = tgtP[q * B + tid];        // coalesced, L2-resident
            float4 g1 = tgtP[q * B + 256 + tid];
#pragma unroll
            for (int mi = 0; mi < MCHUNK; ++mi) {
                float4 mv = smem[mi * (T / 2) + q];   // uniform -> LDS broadcast
                float dx, dy;
                dx = mv.x - g0.x; dy = mv.y - g0.y;
                acc0[mi] += __builtin_amdgcn_sqrtf(fmaf(dx, dx, dy * dy));
                dx = mv.z - g0.z; dy = mv.w - g0.w;
                acc0[mi] += __builtin_amdgcn_sqrtf(fmaf(dx, dx, dy * dy));
                dx = mv.x - g1.x; dy = mv.y - g1.y;
                acc1[mi] += __builtin_amdgcn_sqrtf(fmaf(dx, dx, dy * dy));
                dx = mv.z - g1.z; dy = mv.w - g1.w;
                acc1[mi] += __builtin_amdgcn_sqrtf(fmaf(dx, dx, dy * dy));
            }
        }

        float bv0 = acc0[0]; int bi0 = m0;        // ascending m -> lowest idx on tie
        float bv1 = acc1[0]; int bi1 = m0;
#pragma unroll
        for (int mi = 1; mi < MCHUNK; ++mi) {
            if (acc0[mi] < bv0) { bv0 = acc0[mi]; bi0 = m0 + mi; }
            if (acc1[mi] < bv1) { bv1 = acc1[mi]; bi1 = m0 + mi; }
        }
        // [ch][b] layout -> coalesced stores
        pvalT[(size_t)ch * B + tid]       = ((u64)__float_as_uint(bv0) << 32) | (unsigned int)bi0;
        pvalT[(size_t)ch * B + 256 + tid] = ((u64)__float_as_uint(bv1) << 32) | (unsigned int)bi1;
    }
    grid.sync();

    // ---------------- Phase 2: block = b. argmin + LSE + NLL + mean -------------
    {
        const int b = bid;
        u64 p0 = pvalT[(size_t)tid * B + b];          // ch = tid
        u64 p1 = pvalT[(size_t)(tid + 256) * B + b];  // ch = tid+256
        smu[tid] = p0 < p1 ? p0 : p1;
        __syncthreads();
        for (int s = 128; s > 0; s >>= 1) {
            if (tid < s) { u64 o = smu[tid + s]; if (o < smu[tid]) smu[tid] = o; }
            __syncthreads();
        }
        const int idx = (int)(unsigned int)(smu[0] & 0xFFFFFFFFULL);
        __syncthreads();

        const float4* row = (const float4*)(preds + (size_t)b * M);  // 1024 float4
        float4 v[4];
        float mx = -INFINITY;
#pragma unroll
        for (int j = 0; j < 4; ++j) {
            v[j] = row[tid + j * 256];
            mx = fmaxf(mx, fmaxf(fmaxf(v[j].x, v[j].y), fmaxf(v[j].z, v[j].w)));
        }
        red[tid] = mx; __syncthreads();
        for (int s = 128; s > 0; s >>= 1) {
            if (tid < s) red[tid] = fmaxf(red[tid], red[tid + s]);
            __syncthreads();
        }
        mx = red[0];
        __syncthreads();

        float sum = 0.f;
#pragma unroll
        for (int j = 0; j < 4; ++j)
            sum += expf(v[j].x - mx) + expf(v[j].y - mx) + expf(v[j].z - mx) + expf(v[j].w - mx);
        red[tid] = sum; __syncthreads();
        for (int s = 128; s > 0; s >>= 1) {
            if (tid < s) red[tid] += red[tid + s];
            __syncthreads();
        }

        if (tid == 0) {
            float lse = mx + logf(red[0]);
            float nll = lse - preds[(size_t)b * M + idx];
            atomicAdd(out, nll * (1.0f / B));     // out[0] zeroed in phase 0
            out[1 + b] = (float)idx;
        }
    }
}

extern "C" void kernel_launch(void* const* d_in, const int* in_sizes, int n_in,
                              void* d_out, int out_size, void* d_ws, size_t ws_size,
                              hipStream_t stream) {
    const float* preds  = (const float*)d_in[0];  // (512, 4096)
    const float* target = (const float*)d_in[1];  // (512, 1, 48, 2)
    const float* memory = (const float*)d_in[2];  // (4096, 48, 2)
    float* out = (float*)d_out;                   // [loss, idx[512]]

    char* ws = (char*)d_ws;
    u64* pvalT   = (u64*)ws;                                  // 512*512*8 = 2 MiB
    float4* tgtP = (float4*)(ws + (size_t)2 * 1024 * 1024);   // 24*512*16 = 192 KiB

    void* args[] = {(void*)&preds, (void*)&target, (void*)&memory,
                    (void*)&out, (void*)&pvalT, (void*)&tgtP};
    hipLaunchCooperativeKernel((const void*)k_fused, dim3(NCH), dim3(256),
                               args, 0, stream);
}

// Round 7
// 44.606 us; speedup vs baseline: 3.3230x; 3.3230x over previous
//
#include <hip/hip_runtime.h>
#include <math.h>

typedef unsigned long long u64;

#define B 512
#define M 4096
#define T 48
#define MCHUNK 8
#define NCH (M / MCHUNK)     // 512 chunks
#define BGRP 128             // b's per k_dist block (2 per lane)
#define QW 6                 // float4 (=2t) per wave slice: 4 waves * 6 * 2t = 48t

// ws layout (bytes):
//   [0, 2 MiB)            pval[b][ch]: packed (float_bits(dist)<<32 | m), u64
//   [2 MiB, +192 KiB)     tgtP[q][b]: float4 (t=2q,2q+1), q<24

// ---- Kernel 0: pack target (B,T,2) -> tgtP[q][b]; zero loss slot ----------
__global__ __launch_bounds__(256) void k_prep(const float* __restrict__ target,
                                              float4* __restrict__ tgtP,
                                              float* __restrict__ out0) {
    int i = blockIdx.x * 256 + threadIdx.x;        // B*T/2 = 12288 float4
    if (i == 0) out0[0] = 0.0f;
    int b = i / (T / 2), q = i - b * (T / 2);
    float4 v = *(const float4*)(target + (size_t)b * (T * 2) + 4 * q);
    tgtP[q * B + b] = v;
}

// ---- Kernel 1: distance. wave w owns t-slice [12w,12w+12); lane owns 2 b's -
__global__ __launch_bounds__(256, 4) void k_dist(const float4* __restrict__ tgtP,
                                                 const float* __restrict__ memory,
                                                 u64* __restrict__ pval) {
    const int tid  = threadIdx.x;
    const int lane = tid & 63;
    const int w    = tid >> 6;
    const int ch   = blockIdx.x;
    const int m0   = ch * MCHUNK;
    const int b0   = blockIdx.y * BGRP;

    __shared__ float4 smem[MCHUNK * (T / 2)];      // 192 float4 = 3 KB
    __shared__ float  part[4][MCHUNK][BGRP];       // 16 KB partial t-sums
    __shared__ float  sum[MCHUNK][BGRP];           // 4 KB

    if (tid < MCHUNK * (T / 2))
        smem[tid] = ((const float4*)memory)[(size_t)m0 * (T / 2) + tid];

    // per-lane target slices: 6 float4 for each of 2 b's (static-indexed)
    float4 ga[QW], gb[QW];
#pragma unroll
    for (int j = 0; j < QW; ++j) {
        ga[j] = tgtP[(QW * w + j) * B + b0 + lane];        // coalesced
        gb[j] = tgtP[(QW * w + j) * B + b0 + 64 + lane];
    }
    __syncthreads();

    float acc0[MCHUNK], acc1[MCHUNK];
#pragma unroll
    for (int mi = 0; mi < MCHUNK; ++mi) { acc0[mi] = 0.f; acc1[mi] = 0.f; }

#pragma unroll
    for (int j = 0; j < QW; ++j) {
        const float4 g0 = ga[j], g1 = gb[j];
#pragma unroll
        for (int mi = 0; mi < MCHUNK; ++mi) {
            float4 mv = smem[mi * (T / 2) + QW * w + j];   // uniform -> broadcast
            float dx, dy;
            dx = mv.x - g0.x; dy = mv.y - g0.y;
            acc0[mi] += __builtin_amdgcn_sqrtf(fmaf(dx, dx, dy * dy));
            dx = mv.z - g0.z; dy = mv.w - g0.w;
            acc0[mi] += __builtin_amdgcn_sqrtf(fmaf(dx, dx, dy * dy));
            dx = mv.x - g1.x; dy = mv.y - g1.y;
            acc1[mi] += __builtin_amdgcn_sqrtf(fmaf(dx, dx, dy * dy));
            dx = mv.z - g1.z; dy = mv.w - g1.w;
            acc1[mi] += __builtin_amdgcn_sqrtf(fmaf(dx, dx, dy * dy));
        }
    }

#pragma unroll
    for (int mi = 0; mi < MCHUNK; ++mi) {
        part[w][mi][lane]      = acc0[mi];
        part[w][mi][64 + lane] = acc1[mi];
    }
    __syncthreads();

    // sum the 4 wave-partials: 1024 items, 4 per thread
#pragma unroll
    for (int k = 0; k < 4; ++k) {
        int item = k * 256 + tid;
        int mi = item >> 7, bb = item & (BGRP - 1);
        sum[mi][bb] = part[0][mi][bb] + part[1][mi][bb]
                    + part[2][mi][bb] + part[3][mi][bb];
    }
    __syncthreads();

    // per-b argmin over the 8 chunk members (ascending -> lowest idx on tie)
    if (tid < BGRP) {
        float bv = sum[0][tid]; int bi = m0;
#pragma unroll
        for (int mi = 1; mi < MCHUNK; ++mi)
            if (sum[mi][tid] < bv) { bv = sum[mi][tid]; bi = m0 + mi; }
        pval[(size_t)(b0 + tid) * NCH + ch] =
            ((u64)__float_as_uint(bv) << 32) | (unsigned int)bi;
    }
}

// ---- Kernel 2: one WAVE per b: argmin + LSE + NLL + mean (shfl only) ------
__global__ __launch_bounds__(256) void k_post(const float* __restrict__ preds,
                                              const u64* __restrict__ pval,
                                              float* __restrict__ out) {
    const int lane = threadIdx.x & 63;
    const int wv   = threadIdx.x >> 6;
    const int b    = blockIdx.x * 4 + wv;

    // argmin over NCH=512 chunk minima (u64 min == (dist, idx) lexmin)
    u64 best = 0xFFFFFFFFFFFFFFFFULL;
#pragma unroll
    for (int j = 0; j < NCH / 64; ++j) {           // 8, coalesced
        u64 p = pval[(size_t)b * NCH + j * 64 + lane];
        if (p < best) best = p;
    }
#pragma unroll
    for (int s = 32; s > 0; s >>= 1) {
        u64 o = __shfl_down(best, s);
        if (o < best) best = o;
    }
    best = __shfl(best, 0);
    const int idx = (int)(unsigned int)(best & 0xFFFFFFFFULL);

    // LSE over preds row (64 floats per lane, coalesced float4)
    const float4* row = (const float4*)(preds + (size_t)b * M);  // 1024 float4
    float4 v[16];
    float mx = -INFINITY;
#pragma unroll
    for (int j = 0; j < 16; ++j) {
        v[j] = row[j * 64 + lane];
        mx = fmaxf(mx, fmaxf(fmaxf(v[j].x, v[j].y), fmaxf(v[j].z, v[j].w)));
    }
#pragma unroll
    for (int s = 32; s > 0; s >>= 1) mx = fmaxf(mx, __shfl_down(mx, s));
    mx = __shfl(mx, 0);

    float sum = 0.f;
#pragma unroll
    for (int j = 0; j < 16; ++j)
        sum += expf(v[j].x - mx) + expf(v[j].y - mx) + expf(v[j].z - mx) + expf(v[j].w - mx);
#pragma unroll
    for (int s = 32; s > 0; s >>= 1) sum += __shfl_down(sum, s);

    if (lane == 0) {
        float lse = mx + logf(sum);
        float nll = lse - preds[(size_t)b * M + idx];
        atomicAdd(out, nll * (1.0f / B));          // out[0] zeroed by k_prep
        out[1 + b] = (float)idx;
    }
}

extern "C" void kernel_launch(void* const* d_in, const int* in_sizes, int n_in,
                              void* d_out, int out_size, void* d_ws, size_t ws_size,
                              hipStream_t stream) {
    const float* preds  = (const float*)d_in[0];  // (512, 4096)
    const float* target = (const float*)d_in[1];  // (512, 1, 48, 2)
    const float* memory = (const float*)d_in[2];  // (4096, 48, 2)
    float* out = (float*)d_out;                   // [loss, idx[512]]

    char* ws = (char*)d_ws;
    u64* pval    = (u64*)ws;                                  // 512*512*8 = 2 MiB
    float4* tgtP = (float4*)(ws + (size_t)2 * 1024 * 1024);   // 192 KiB

    k_prep<<<(B * T / 2) / 256, 256, 0, stream>>>(target, tgtP, out);
    dim3 g1(NCH, B / BGRP);                       // 512 x 4 = 2048 blocks
    k_dist<<<g1, 256, 0, stream>>>(tgtP, memory, pval);
    k_post<<<B / 4, 256, 0, stream>>>(preds, pval, out);
}